// Round 10
// baseline (1446.560 us; speedup 1.0000x reference)
//
#include <hip/hip_runtime.h>
#include <hip/hip_bf16.h>

// EntityTable: B=16,T=2048,D=1024,N_E=8,D_E=64
// Phase A (parallel): hp = h@Wi^T + bi ; logits = h@ek^T/32 ; w = softmax(logits)
//                     P  = W_ih @ hp   (entity-independent input-gate projection)
// Phase B (sequential scan over T): per cell (b,n):
//   gx_k = w*P_k + b_ih_k ; gh_k = W_hh[k]·s + b_hh_k
//   r=sig(gx0+gh0) z=sig(gx1+gh1) n=tanh(gx2 + r*gh2) ; s' = (1-z)n + z s
//
// Round-10 scan: r5's single-wave-per-cell structure (best measured: 842us,
// one LDS hop, zero barriers) + amdgpu_waves_per_eu(1,1) (r9-proven to raise
// the RA budget so all 192 weight floats stay register-resident; r5 ran with
// only ~1/3 resident -> per-step weight reloads whose vmcnt waits dragged the
// P/route prefetch latency onto the serial path). Accumulators split into
// lo/hi chains per gate so chained pk_fma never stalls on dep latency.

constexpr int B_  = 16;
constexpr int T_  = 2048;
constexpr int D_  = 1024;
constexpr int NE  = 8;
constexpr int DE  = 64;
constexpr int G3  = 192;            // 3*DE
constexpr int ROWS = B_ * T_;       // 32768
constexpr int OUT1OFF = ROWS * NE * DE;  // 16777216

typedef __attribute__((ext_vector_type(2))) float f32x2;
typedef __attribute__((ext_vector_type(4))) float f32x4;

__device__ __forceinline__ void pkacc(f32x2& acc, f32x2 w, f32x2 s) {
    asm("v_pk_fma_f32 %0, %1, %2, %0" : "+v"(acc) : "v"(w), "v"(s));
}

// ---------------- Kernel T: transpose Wi -> WT4 ----------------
__global__ __launch_bounds__(256) void wt_kernel(
    const float* __restrict__ Wi, float* __restrict__ WT4)
{
    const int o  = blockIdx.x;     // 64 blocks
    const int dq = threadIdx.x;    // 256 threads
    const float4 v = *(const float4*)&Wi[o * D_ + dq * 4];
    *(float4*)&WT4[(dq * 64 + o) * 4] = v;
}

// ---------------- Kernel A: projection + routing + P ----------------
constexpr int RPB = 32;   // rows per block
constexpr int CH  = 128;  // K-chunk

__global__ __launch_bounds__(256) void proj_kernel(
    const float* __restrict__ h,   const float* __restrict__ ek,
    const float* __restrict__ WT4, const float* __restrict__ bi,
    const float* __restrict__ Wih,
    float* __restrict__ Pout, float* __restrict__ wout)
{
    __shared__ float hch[RPB][CH];   // 16 KB
    __shared__ float hp[RPB][DE];    // 8 KB
    __shared__ float lg[RPB][NE];    // 1 KB

    const int tid = threadIdx.x;
    const int brow = blockIdx.x * RPB;
    const int w = tid >> 6;          // wave 0..3
    const int o = tid & 63;          // lane = output index for hp
    const int n  = o & 7;            // entity for logit partial
    const int sl = o >> 3;           // K-slice for logit partial

    float acc[8], accl[8];
#pragma unroll
    for (int r = 0; r < 8; ++r) { acc[r] = 0.f; accl[r] = 0.f; }

    for (int kc = 0; kc < D_; kc += CH) {
        __syncthreads();
#pragma unroll
        for (int i = 0; i < 4; ++i) {
            int idx = tid + i * 256;
            int lr = idx >> 5;
            int c4 = (idx & 31) * 4;
            *(float4*)&hch[lr][c4] =
                *(const float4*)&h[(size_t)(brow + lr) * D_ + kc + c4];
        }
        __syncthreads();

        for (int d4 = 0; d4 < CH / 4; ++d4) {
            const float4 wt = *(const float4*)&WT4[((kc >> 2) + d4) * 256 + (o << 2)];
#pragma unroll
            for (int r = 0; r < 8; ++r) {
                const float4 h4 = *(const float4*)&hch[w * 8 + r][d4 * 4];
                acc[r] = fmaf(wt.x, h4.x,
                         fmaf(wt.y, h4.y,
                         fmaf(wt.z, h4.z,
                         fmaf(wt.w, h4.w, acc[r]))));
            }
        }
#pragma unroll
        for (int i4 = 0; i4 < 4; ++i4) {
            const int dl = sl * 16 + i4 * 4;
            const float4 e4 = *(const float4*)&ek[n * D_ + kc + dl];
#pragma unroll
            for (int r = 0; r < 8; ++r) {
                const float4 h4 = *(const float4*)&hch[w * 8 + r][dl];
                accl[r] = fmaf(e4.x, h4.x,
                          fmaf(e4.y, h4.y,
                          fmaf(e4.z, h4.z,
                          fmaf(e4.w, h4.w, accl[r]))));
            }
        }
    }

    const float biv = bi[o];
#pragma unroll
    for (int r = 0; r < 8; ++r) hp[w * 8 + r][o] = acc[r] + biv;

#pragma unroll
    for (int r = 0; r < 8; ++r) {
        accl[r] += __shfl_xor(accl[r], 8);
        accl[r] += __shfl_xor(accl[r], 16);
        accl[r] += __shfl_xor(accl[r], 32);
    }
    if (sl == 0) {
#pragma unroll
        for (int r = 0; r < 8; ++r) lg[w * 8 + r][n] = accl[r] * 0.03125f;
    }
    __syncthreads();

    if (tid < RPB) {
        const int lr = tid;
        float v[NE];
        float m = -1e30f;
#pragma unroll
        for (int e = 0; e < NE; ++e) { v[e] = lg[lr][e]; m = fmaxf(m, v[e]); }
        float s = 0.f;
#pragma unroll
        for (int e = 0; e < NE; ++e) { v[e] = __expf(v[e] - m); s += v[e]; }
        const float inv = 1.f / s;
#pragma unroll
        for (int e = 0; e < NE; ++e)
            wout[(size_t)(brow + lr) * NE + e] = v[e] * inv;
    }

    if (tid < G3) {
        const int k = tid;
        for (int lr0 = 0; lr0 < RPB; lr0 += 8) {
            float pacc[8];
#pragma unroll
            for (int r = 0; r < 8; ++r) pacc[r] = 0.f;
            for (int d4 = 0; d4 < DE / 4; ++d4) {
                const float4 wv = *(const float4*)&Wih[k * DE + d4 * 4];
#pragma unroll
                for (int r = 0; r < 8; ++r) {
                    const float4 h4 = *(const float4*)&hp[lr0 + r][d4 * 4];
                    pacc[r] = fmaf(wv.x, h4.x,
                              fmaf(wv.y, h4.y,
                              fmaf(wv.z, h4.z,
                              fmaf(wv.w, h4.w, pacc[r]))));
                }
            }
#pragma unroll
            for (int r = 0; r < 8; ++r)
                Pout[(size_t)(brow + lr0 + r) * G3 + k] = pacc[r];
        }
    }
}

// ---------------- Kernel B: one-wave-per-cell GRU scan (fully resident) ----------------
#define DW(pre, base, q) \
    f32x4 pre##q = *(const f32x4*)&Whh[(size_t)(base + j) * 64 + 4 * (q)];
#define DW16(pre, base) \
    DW(pre, base, 0)  DW(pre, base, 1)  DW(pre, base, 2)  DW(pre, base, 3)  \
    DW(pre, base, 4)  DW(pre, base, 5)  DW(pre, base, 6)  DW(pre, base, 7)  \
    DW(pre, base, 8)  DW(pre, base, 9)  DW(pre, base, 10) DW(pre, base, 11) \
    DW(pre, base, 12) DW(pre, base, 13) DW(pre, base, 14) DW(pre, base, 15)

#define KA(pre, q) asm volatile("" : "+v"(pre##q));
#define KA16(pre) \
    KA(pre, 0)  KA(pre, 1)  KA(pre, 2)  KA(pre, 3)  KA(pre, 4)  KA(pre, 5) \
    KA(pre, 6)  KA(pre, 7)  KA(pre, 8)  KA(pre, 9)  KA(pre, 10) KA(pre, 11) \
    KA(pre, 12) KA(pre, 13) KA(pre, 14) KA(pre, 15)

// two independent chains per gate (lo/hi) so dep latency never stalls issue
#define MACQ(q) { \
    const f32x4 s4 = *(const f32x4*)&s_l[4 * (q)]; \
    const f32x2 lo = s4.lo, hi = s4.hi; \
    pkacc(aRa, wr##q.lo, lo); pkacc(aRb, wr##q.hi, hi); \
    pkacc(aZa, wz##q.lo, lo); pkacc(aZb, wz##q.hi, hi); \
    pkacc(aNa, wn##q.lo, lo); pkacc(aNb, wn##q.hi, hi); }
#define MAC16() \
    MACQ(0)  MACQ(1)  MACQ(2)  MACQ(3)  MACQ(4)  MACQ(5)  MACQ(6)  MACQ(7) \
    MACQ(8)  MACQ(9)  MACQ(10) MACQ(11) MACQ(12) MACQ(13) MACQ(14) MACQ(15)

__global__ __launch_bounds__(64)
__attribute__((amdgpu_waves_per_eu(1, 1)))
void scan_kernel(
    const float* __restrict__ P,   const float* __restrict__ route,
    const float* __restrict__ Whh, const float* __restrict__ bih,
    const float* __restrict__ bhh, const float* __restrict__ e0,
    float* __restrict__ out, int write1)
{
    __shared__ __align__(16) float s_l[DE];

    // XCD co-location (halves scan FETCH, time-neutral)
    const int g   = blockIdx.x;          // 0..127
    const int xcd = g & 7;
    const int ii  = g >> 3;              // 0..15
    const int b   = xcd + 8 * (ii & 1);
    const int n   = ii >> 1;
    const int j   = threadIdx.x;         // 0..63

    // 48 named f32x4 = 192 weight floats, register-resident under (1,1) budget
    DW16(wr, 0)
    DW16(wz, 64)
    DW16(wn, 128)
    KA16(wr) KA16(wz) KA16(wn)

    const float Br   = bih[j] + bhh[j];            // combined r bias
    const float Bz   = bih[64 + j] + bhh[64 + j];  // combined z bias
    const float bin_ = bih[128 + j];
    const float bhn_ = bhh[128 + j];

    const size_t row0 = (size_t)b * T_;
    float s_reg = e0[n * DE + j];
    s_l[j] = s_reg;                      // same-wave ds ordering, no barrier

    const float* Pb = P + row0 * G3;
    const float* wb = route + row0 * NE + n;
    float* op = out + row0 * (size_t)(NE * DE) + n * DE + j;

    // software prefetch, depth = 2 steps
    float pr0 = Pb[j],       pr1 = Pb[G3 + j];
    float pz0 = Pb[64 + j],  pz1 = Pb[G3 + 64 + j];
    float pn0 = Pb[128 + j], pn1 = Pb[G3 + 128 + j];
    float wv0 = wb[0],       wv1 = wb[NE];

    for (int t0 = 0; t0 < T_; t0 += 2) {
        const int tb = (t0 + 2 < T_) ? (t0 + 2) : t0;   // tail clamp (harmless)
        const float qr0 = Pb[(size_t)(tb) * G3 + j];
        const float qz0 = Pb[(size_t)(tb) * G3 + 64 + j];
        const float qn0 = Pb[(size_t)(tb) * G3 + 128 + j];
        const float qw0 = wb[tb * NE];
        const float qr1 = Pb[(size_t)(tb + 1) * G3 + j];
        const float qz1 = Pb[(size_t)(tb + 1) * G3 + 64 + j];
        const float qn1 = Pb[(size_t)(tb + 1) * G3 + 128 + j];
        const float qw1 = wb[(tb + 1) * NE];

#pragma unroll
        for (int i = 0; i < 2; ++i) {
            const float pri = i ? pr1 : pr0;
            const float pzi = i ? pz1 : pz0;
            const float pni = i ? pn1 : pn0;
            const float wvi = i ? wv1 : wv0;

            f32x2 aRa = {0.f, 0.f}, aRb = {0.f, 0.f};
            f32x2 aZa = {0.f, 0.f}, aZb = {0.f, 0.f};
            f32x2 aNa = {0.f, 0.f}, aNb = {0.f, 0.f};
            MAC16()

            const f32x2 aR = aRa + aRb, aZ = aZa + aZb, aN = aNa + aNb;
            const float argR = (aR.x + aR.y) + fmaf(wvi, pri, Br);
            const float argZ = (aZ.x + aZ.y) + fmaf(wvi, pzi, Bz);
            const float rr = __builtin_amdgcn_rcpf(1.f + __expf(-argR));
            const float zz = __builtin_amdgcn_rcpf(1.f + __expf(-argZ));
            const float u  = fmaf(wvi, pni, bin_);
            const float v  = (aN.x + aN.y) + bhn_;
            const float x  = fmaf(rr, v, u);
            const float nn = fmaf(2.f, __builtin_amdgcn_rcpf(1.f + __expf(-2.f * x)), -1.f);
            const float snew = fmaf(zz, s_reg - nn, nn);   // (1-z)n + z s
            s_reg = snew;
            s_l[j] = snew;               // the single cross-lane hop
            op[(size_t)(t0 + i) * (NE * DE)] = snew;
            if (write1) op[OUT1OFF + (size_t)(t0 + i) * (NE * DE)] = snew;
        }

        pr0 = qr0; pz0 = qz0; pn0 = qn0; wv0 = qw0;
        pr1 = qr1; pz1 = qz1; pn1 = qn1; wv1 = qw1;
    }
}

// ---------------- Kernel C: replicate out0 -> out1 (stash path) ----------------
__global__ __launch_bounds__(256) void copy_kernel(
    const float4* __restrict__ src, float4* __restrict__ dst, int n4)
{
    int i = blockIdx.x * 256 + threadIdx.x;
    const int stride = gridDim.x * 256;
    for (; i < n4; i += stride) dst[i] = src[i];
}

extern "C" void kernel_launch(void* const* d_in, const int* in_sizes, int n_in,
                              void* d_out, int out_size, void* d_ws, size_t ws_size,
                              hipStream_t stream) {
    const float* h_seq = (const float*)d_in[0];
    const float* ek    = (const float*)d_in[1];
    const float* Wi    = (const float*)d_in[2];
    const float* bi    = (const float*)d_in[3];
    const float* Wih   = (const float*)d_in[4];
    const float* Whh   = (const float*)d_in[5];
    const float* bih   = (const float*)d_in[6];
    const float* bhh   = (const float*)d_in[7];
    const float* e0    = (const float*)d_in[8];
    float* out = (float*)d_out;

    const size_t need = (size_t)ROWS * (G3 + NE) * sizeof(float)
                      + (size_t)DE * D_ * sizeof(float);  // ~26.5 MB
    float* wbuf;
    int write1;
    if (ws_size >= need) {
        wbuf = (float*)d_ws;
        write1 = 1;                    // scan writes both output copies
    } else {
        wbuf = out + OUT1OFF;          // stash in out1; copy at the end
        write1 = 0;
    }
    float* Pbuf = wbuf + (size_t)ROWS * NE;
    float* WT4  = Pbuf + (size_t)ROWS * G3;

    wt_kernel<<<DE, 256, 0, stream>>>(Wi, WT4);
    proj_kernel<<<ROWS / RPB, 256, 0, stream>>>(h_seq, ek, WT4, bi, Wih, Pbuf, wbuf);
    scan_kernel<<<B_ * NE, 64, 0, stream>>>(Pbuf, wbuf, Whh, bih, bhh, e0, out, write1);

    if (!write1) {
        copy_kernel<<<2048, 256, 0, stream>>>((const float4*)out,
                                              (float4*)(out + OUT1OFF), OUT1OFF / 4);
    }
}